// Round 4
// baseline (351.476 us; speedup 1.0000x reference)
//
#include <hip/hip_runtime.h>

// OrdinalCrossEntropyLoss: out = sum_n sum_{i < t_n} relu(logits[n,i] - logits[n,t_n])
// N = 262144 rows, C = 512 classes, fp32 logits, int targets, scalar fp32 out.
//
// Memory-bound; read only the prefix [0,t) of each row (~half the bytes).
// R3 lesson: per-group full vmcnt drain + (suspected) 2 waves/SIMD occupancy
// exposed ~2000cyc loaded latency -> 4.25 TB/s. Fix: explicit software
// pipeline — 16 row-pairs, 4-slot register ring, prefetch distance 3
// (~12 loads in flight across consumption), fully unrolled so ring indices
// are static; __launch_bounds__(256,4) caps VGPR<=128 for 4 waves/SIMD.

constexpr int C = 512;
constexpr int ROWS_PER_WAVE = 32;
constexpr int NPAIR = ROWS_PER_WAVE / 2;   // 16

__device__ __forceinline__ void acc4(float& acc, const float4 v, int i, int t, float tl) {
    acc += (i + 0 < t) ? fmaxf(v.x - tl, 0.0f) : 0.0f;
    acc += (i + 1 < t) ? fmaxf(v.y - tl, 0.0f) : 0.0f;
    acc += (i + 2 < t) ? fmaxf(v.z - tl, 0.0f) : 0.0f;
    acc += (i + 3 < t) ? fmaxf(v.w - tl, 0.0f) : 0.0f;
}

__global__ __launch_bounds__(256, 4) void ordinal_ce_kernel(
    const float* __restrict__ logits,
    const int* __restrict__ targets,
    float* __restrict__ out,
    int N)
{
    const int lane    = threadIdx.x & 63;
    const int wave_id = (blockIdx.x * blockDim.x + threadIdx.x) >> 6;
    const int rowbase = wave_id * ROWS_PER_WAVE;

    float acc = 0.0f;

    if (rowbase < N) {
        // --- metadata preload: lanes 0..31 own one row each (coalesced t, 32
        // parallel tl gathers). Afterwards t/tl come from registers via shfl.
        int   t_l  = 0;
        float tl_l = 0.0f;
        if (lane < ROWS_PER_WAVE && rowbase + lane < N) {
            const int r = rowbase + lane;
            t_l  = targets[r];
            tl_l = logits[(size_t)r * C + t_l];
        }

        const int i0 = lane * 4;          // chunk-0 element index
        const int i1 = i0 + 256;          // chunk-1 element index

        if (N - rowbase >= ROWS_PER_WAVE) {
            // ---------------- pipelined main path ----------------
            float4 a0[4], a1[4], b0[4], b1[4];   // ring slots (static idx only)
            const float4 z4 = make_float4(0.f, 0.f, 0.f, 0.f);

#define ISSUE(S, P) do {                                                      \
        const int   ta = __shfl(t_l, 2 * (P), 64);                            \
        const int   tb = __shfl(t_l, 2 * (P) + 1, 64);                        \
        const float* __restrict__ pa =                                        \
            logits + (size_t)(rowbase + 2 * (P)) * C;                         \
        const float* __restrict__ pb = pa + C;                                \
        a0[S] = z4; a1[S] = z4; b0[S] = z4; b1[S] = z4;                       \
        if (i0 < ta) a0[S] = *reinterpret_cast<const float4*>(pa + i0);       \
        if (i1 < ta) a1[S] = *reinterpret_cast<const float4*>(pa + i1);       \
        if (i0 < tb) b0[S] = *reinterpret_cast<const float4*>(pb + i0);       \
        if (i1 < tb) b1[S] = *reinterpret_cast<const float4*>(pb + i1);       \
    } while (0)

#define CONSUME(S, P) do {                                                    \
        const int   ta  = __shfl(t_l,  2 * (P), 64);                          \
        const float tla = __shfl(tl_l, 2 * (P), 64);                          \
        const int   tb  = __shfl(t_l,  2 * (P) + 1, 64);                      \
        const float tlb = __shfl(tl_l, 2 * (P) + 1, 64);                      \
        acc4(acc, a0[S], i0, ta, tla);                                        \
        acc4(acc, a1[S], i1, ta, tla);                                        \
        acc4(acc, b0[S], i0, tb, tlb);                                        \
        acc4(acc, b1[S], i1, tb, tlb);                                        \
    } while (0)

            ISSUE(0, 0); ISSUE(1, 1); ISSUE(2, 2);
            #pragma unroll
            for (int p = 0; p < NPAIR; ++p) {
                if (p + 3 < NPAIR) ISSUE((p + 3) & 3, p + 3);
                CONSUME(p & 3, p);
            }
#undef ISSUE
#undef CONSUME
        } else {
            // ---------------- generic tail path (not hit at N=262144) -------
            const int rows = N - rowbase;
            for (int r = 0; r < rows; ++r) {
                const int   t  = __shfl(t_l,  r, 64);
                const float tl = __shfl(tl_l, r, 64);
                if (t <= 0) continue;
                const float* __restrict__ rp = logits + (size_t)(rowbase + r) * C;
                float4 c0 = make_float4(0.f, 0.f, 0.f, 0.f);
                float4 c1 = make_float4(0.f, 0.f, 0.f, 0.f);
                if (i0 < t) c0 = *reinterpret_cast<const float4*>(rp + i0);
                if (i1 < t) c1 = *reinterpret_cast<const float4*>(rp + i1);
                acc4(acc, c0, i0, t, tl);
                acc4(acc, c1, i1, t, tl);
            }
        }
    }

    // --- wave reduction (64 lanes) ---
    #pragma unroll
    for (int off = 32; off > 0; off >>= 1)
        acc += __shfl_down(acc, off, 64);

    // --- block reduction: 4 waves ---
    __shared__ float wave_sums[4];
    const int wib = threadIdx.x >> 6;
    if (lane == 0) wave_sums[wib] = acc;
    __syncthreads();
    if (threadIdx.x == 0) {
        const float s = wave_sums[0] + wave_sums[1] + wave_sums[2] + wave_sums[3];
        atomicAdd(out, s);
    }
}

extern "C" void kernel_launch(void* const* d_in, const int* in_sizes, int n_in,
                              void* d_out, int out_size, void* d_ws, size_t ws_size,
                              hipStream_t stream) {
    const float* logits  = (const float*)d_in[0];
    const int*   targets = (const int*)d_in[1];
    float*       out     = (float*)d_out;

    const int N = in_sizes[1];                 // 262144 rows

    // d_out is poisoned and not re-poisoned between replays; we accumulate.
    hipMemsetAsync(out, 0, sizeof(float) * out_size, stream);

    const int block = 256;
    const int rows_per_block = (block / 64) * ROWS_PER_WAVE;    // 128
    const int grid = (N + rows_per_block - 1) / rows_per_block; // 2048
    ordinal_ce_kernel<<<grid, block, 0, stream>>>(logits, targets, out, N);
}

// Round 5
// 100.860 us; speedup vs baseline: 3.4848x; 3.4848x over previous
//
#include <hip/hip_runtime.h>

// OrdinalCrossEntropyLoss: out = sum_n sum_{i < t_n} relu(logits[n,i] - logits[n,t_n])
// N = 262144 rows, C = 512 classes, fp32 logits, int targets, scalar fp32 out.
//
// Memory-bound; read only the prefix [0,t) of each row (~half the bytes).
// R4 lesson: register-ring with arrays + launch_bounds cap spilled to scratch
// (WRITE_SIZE=676MB, 5x regression). Fix: double-buffer with NAMED float4
// variables (no arrays, all lexical), prefetch distance 1 -> 8 loads in
// flight while consuming previous 8; no min-waves cap so nothing spills.

constexpr int C = 512;
constexpr int ROWS_PER_WAVE = 32;          // 8 groups of 4 rows

__device__ __forceinline__ void acc4(float& acc, const float4 v, int i, int t, float tl) {
    acc += (i + 0 < t) ? fmaxf(v.x - tl, 0.0f) : 0.0f;
    acc += (i + 1 < t) ? fmaxf(v.y - tl, 0.0f) : 0.0f;
    acc += (i + 2 < t) ? fmaxf(v.z - tl, 0.0f) : 0.0f;
    acc += (i + 3 < t) ? fmaxf(v.w - tl, 0.0f) : 0.0f;
}

__global__ __launch_bounds__(256) void ordinal_ce_kernel(
    const float* __restrict__ logits,
    const int* __restrict__ targets,
    float* __restrict__ out,
    int N)
{
    const int lane    = threadIdx.x & 63;
    const int wave_id = (blockIdx.x * blockDim.x + threadIdx.x) >> 6;
    const int rowbase = wave_id * ROWS_PER_WAVE;

    float acc = 0.0f;

    if (rowbase < N) {
        // Metadata preload: lanes 0..31 own one row each (coalesced targets,
        // 32 parallel tl gathers). Later reads come from registers via shfl.
        int   t_l  = 0;
        float tl_l = 0.0f;
        if (lane < ROWS_PER_WAVE && rowbase + lane < N) {
            const int r = rowbase + lane;
            t_l  = targets[r];
            tl_l = logits[(size_t)r * C + t_l];
        }

        const int i0 = lane * 4;          // chunk-0 element index
        const int i1 = i0 + 256;          // chunk-1 element index
        const float4 z4 = make_float4(0.f, 0.f, 0.f, 0.f);

        if (N - rowbase >= ROWS_PER_WAVE) {
            // Two named buffers, 8 float4 each (4 rows x 2 chunks). No arrays.
            float4 A00, A01, A10, A11, A20, A21, A30, A31;
            float4 B00, B01, B10, B11, B20, B21, B30, B31;

#define LOADG(Q, P) do {                                                       \
        const int _t0 = __shfl(t_l, 4 * (P) + 0, 64);                          \
        const int _t1 = __shfl(t_l, 4 * (P) + 1, 64);                          \
        const int _t2 = __shfl(t_l, 4 * (P) + 2, 64);                          \
        const int _t3 = __shfl(t_l, 4 * (P) + 3, 64);                          \
        const float* __restrict__ _p =                                         \
            logits + (size_t)(rowbase + 4 * (P)) * C;                          \
        Q##00 = z4; Q##01 = z4; Q##10 = z4; Q##11 = z4;                        \
        Q##20 = z4; Q##21 = z4; Q##30 = z4; Q##31 = z4;                        \
        if (i0 < _t0) Q##00 = *reinterpret_cast<const float4*>(_p + i0);       \
        if (i1 < _t0) Q##01 = *reinterpret_cast<const float4*>(_p + i1);       \
        if (i0 < _t1) Q##10 = *reinterpret_cast<const float4*>(_p + C + i0);   \
        if (i1 < _t1) Q##11 = *reinterpret_cast<const float4*>(_p + C + i1);   \
        if (i0 < _t2) Q##20 = *reinterpret_cast<const float4*>(_p + 2*C + i0); \
        if (i1 < _t2) Q##21 = *reinterpret_cast<const float4*>(_p + 2*C + i1); \
        if (i0 < _t3) Q##30 = *reinterpret_cast<const float4*>(_p + 3*C + i0); \
        if (i1 < _t3) Q##31 = *reinterpret_cast<const float4*>(_p + 3*C + i1); \
    } while (0)

#define CONSG(Q, P) do {                                                       \
        const int   _t0  = __shfl(t_l,  4 * (P) + 0, 64);                      \
        const float _tl0 = __shfl(tl_l, 4 * (P) + 0, 64);                      \
        const int   _t1  = __shfl(t_l,  4 * (P) + 1, 64);                      \
        const float _tl1 = __shfl(tl_l, 4 * (P) + 1, 64);                      \
        const int   _t2  = __shfl(t_l,  4 * (P) + 2, 64);                      \
        const float _tl2 = __shfl(tl_l, 4 * (P) + 2, 64);                      \
        const int   _t3  = __shfl(t_l,  4 * (P) + 3, 64);                      \
        const float _tl3 = __shfl(tl_l, 4 * (P) + 3, 64);                      \
        acc4(acc, Q##00, i0, _t0, _tl0); acc4(acc, Q##01, i1, _t0, _tl0);      \
        acc4(acc, Q##10, i0, _t1, _tl1); acc4(acc, Q##11, i1, _t1, _tl1);      \
        acc4(acc, Q##20, i0, _t2, _tl2); acc4(acc, Q##21, i1, _t2, _tl2);      \
        acc4(acc, Q##30, i0, _t3, _tl3); acc4(acc, Q##31, i1, _t3, _tl3);      \
    } while (0)

            LOADG(A, 0);
            LOADG(B, 1); CONSG(A, 0);
            LOADG(A, 2); CONSG(B, 1);
            LOADG(B, 3); CONSG(A, 2);
            LOADG(A, 4); CONSG(B, 3);
            LOADG(B, 5); CONSG(A, 4);
            LOADG(A, 6); CONSG(B, 5);
            LOADG(B, 7); CONSG(A, 6);
            CONSG(B, 7);
#undef LOADG
#undef CONSG
        } else {
            // Generic tail path (not hit at N=262144).
            const int rows = N - rowbase;
            for (int r = 0; r < rows; ++r) {
                const int   t  = __shfl(t_l,  r, 64);
                const float tl = __shfl(tl_l, r, 64);
                if (t <= 0) continue;
                const float* __restrict__ rp = logits + (size_t)(rowbase + r) * C;
                float4 c0 = z4, c1 = z4;
                if (i0 < t) c0 = *reinterpret_cast<const float4*>(rp + i0);
                if (i1 < t) c1 = *reinterpret_cast<const float4*>(rp + i1);
                acc4(acc, c0, i0, t, tl);
                acc4(acc, c1, i1, t, tl);
            }
        }
    }

    // Wave reduction (64 lanes)
    #pragma unroll
    for (int off = 32; off > 0; off >>= 1)
        acc += __shfl_down(acc, off, 64);

    // Block reduction: 4 waves
    __shared__ float wave_sums[4];
    const int wib = threadIdx.x >> 6;
    if (lane == 0) wave_sums[wib] = acc;
    __syncthreads();
    if (threadIdx.x == 0) {
        const float s = wave_sums[0] + wave_sums[1] + wave_sums[2] + wave_sums[3];
        atomicAdd(out, s);
    }
}

extern "C" void kernel_launch(void* const* d_in, const int* in_sizes, int n_in,
                              void* d_out, int out_size, void* d_ws, size_t ws_size,
                              hipStream_t stream) {
    const float* logits  = (const float*)d_in[0];
    const int*   targets = (const int*)d_in[1];
    float*       out     = (float*)d_out;

    const int N = in_sizes[1];                 // 262144 rows

    // d_out is poisoned and not re-poisoned between replays; we accumulate.
    hipMemsetAsync(out, 0, sizeof(float) * out_size, stream);

    const int block = 256;
    const int rows_per_block = (block / 64) * ROWS_PER_WAVE;    // 128
    const int grid = (N + rows_per_block - 1) / rows_per_block; // 2048
    ordinal_ce_kernel<<<grid, block, 0, stream>>>(logits, targets, out, N);
}

// Round 6
// 56.999 us; speedup vs baseline: 6.1664x; 1.7695x over previous
//
#include <hip/hip_runtime.h>

// OrdinalCrossEntropyLoss: out = sum_n sum_{i < t_n} relu(logits[n,i] - logits[n,t_n])
// N = 262144 rows, C = 512 classes, fp32 logits, int targets, scalar fp32 out.
//
// Memory-bound; read only the prefix [0,t) of each row (~half the bytes).
// R5 lesson: without sched_barrier the scheduler sinks loads to their uses,
// killing the double-buffer (100us). R3's win came from pinning loads ahead
// of consumption. R6 = double-buffer (named vars, no arrays = no spill) with
// sched_barrier(0) between LOADG(next) and CONSG(cur), plus clamped-address
// unconditional loads (cndmask on address, mask in accumulate) instead of
// exec-masked conditional loads.

constexpr int C = 512;
constexpr int ROWS_PER_WAVE = 32;          // 8 groups of 4 rows

__device__ __forceinline__ void acc4(float& acc, const float4 v, int i, int t, float tl) {
    acc += (i + 0 < t) ? fmaxf(v.x - tl, 0.0f) : 0.0f;
    acc += (i + 1 < t) ? fmaxf(v.y - tl, 0.0f) : 0.0f;
    acc += (i + 2 < t) ? fmaxf(v.z - tl, 0.0f) : 0.0f;
    acc += (i + 3 < t) ? fmaxf(v.w - tl, 0.0f) : 0.0f;
}

__global__ __launch_bounds__(256) void ordinal_ce_kernel(
    const float* __restrict__ logits,
    const int* __restrict__ targets,
    float* __restrict__ out,
    int N)
{
    const int lane    = threadIdx.x & 63;
    const int wave_id = (blockIdx.x * blockDim.x + threadIdx.x) >> 6;
    const int rowbase = wave_id * ROWS_PER_WAVE;

    float acc = 0.0f;

    if (rowbase < N) {
        // Metadata preload: lanes 0..31 own one row each (coalesced targets,
        // 32 parallel tl gathers). Later reads come from registers via shfl.
        int   t_l  = 0;
        float tl_l = 0.0f;
        if (lane < ROWS_PER_WAVE && rowbase + lane < N) {
            const int r = rowbase + lane;
            t_l  = targets[r];
            tl_l = logits[(size_t)r * C + t_l];
        }

        const int i0 = lane * 4;          // chunk-0 element index
        const int i1 = i0 + 256;          // chunk-1 element index

        if (N - rowbase >= ROWS_PER_WAVE) {
            // Two named buffers, 8 float4 each (4 rows x 2 chunks). No arrays.
            float4 A00, A01, A10, A11, A20, A21, A30, A31;
            float4 B00, B01, B10, B11, B20, B21, B30, B31;

// Unconditional loads with clamped per-lane offset: lanes past the prefix
// re-read the row-base line (L1/L2 broadcast hit, no HBM cost, no exec mask).
#define LDR(p, i, t) (*reinterpret_cast<const float4*>((p) + (((i) < (t)) ? (i) : 0)))

#define LOADG(Q, P) do {                                                       \
        const int _t0 = __shfl(t_l, 4 * (P) + 0, 64);                          \
        const int _t1 = __shfl(t_l, 4 * (P) + 1, 64);                          \
        const int _t2 = __shfl(t_l, 4 * (P) + 2, 64);                          \
        const int _t3 = __shfl(t_l, 4 * (P) + 3, 64);                          \
        const float* __restrict__ _p =                                         \
            logits + (size_t)(rowbase + 4 * (P)) * C;                          \
        Q##00 = LDR(_p,         i0, _t0);  Q##01 = LDR(_p,         i1, _t0);   \
        Q##10 = LDR(_p + C,     i0, _t1);  Q##11 = LDR(_p + C,     i1, _t1);   \
        Q##20 = LDR(_p + 2 * C, i0, _t2);  Q##21 = LDR(_p + 2 * C, i1, _t2);   \
        Q##30 = LDR(_p + 3 * C, i0, _t3);  Q##31 = LDR(_p + 3 * C, i1, _t3);   \
    } while (0)

#define CONSG(Q, P) do {                                                       \
        const int   _t0  = __shfl(t_l,  4 * (P) + 0, 64);                      \
        const float _tl0 = __shfl(tl_l, 4 * (P) + 0, 64);                      \
        const int   _t1  = __shfl(t_l,  4 * (P) + 1, 64);                      \
        const float _tl1 = __shfl(tl_l, 4 * (P) + 1, 64);                      \
        const int   _t2  = __shfl(t_l,  4 * (P) + 2, 64);                      \
        const float _tl2 = __shfl(tl_l, 4 * (P) + 2, 64);                      \
        const int   _t3  = __shfl(t_l,  4 * (P) + 3, 64);                      \
        const float _tl3 = __shfl(tl_l, 4 * (P) + 3, 64);                      \
        acc4(acc, Q##00, i0, _t0, _tl0); acc4(acc, Q##01, i1, _t0, _tl0);      \
        acc4(acc, Q##10, i0, _t1, _tl1); acc4(acc, Q##11, i1, _t1, _tl1);      \
        acc4(acc, Q##20, i0, _t2, _tl2); acc4(acc, Q##21, i1, _t2, _tl2);      \
        acc4(acc, Q##30, i0, _t3, _tl3); acc4(acc, Q##31, i1, _t3, _tl3);      \
    } while (0)

// Pin: next group's 8 loads must be ISSUED before current group is consumed.
#define SB __builtin_amdgcn_sched_barrier(0)

            LOADG(A, 0);
            LOADG(B, 1); SB; CONSG(A, 0);
            LOADG(A, 2); SB; CONSG(B, 1);
            LOADG(B, 3); SB; CONSG(A, 2);
            LOADG(A, 4); SB; CONSG(B, 3);
            LOADG(B, 5); SB; CONSG(A, 4);
            LOADG(A, 6); SB; CONSG(B, 5);
            LOADG(B, 7); SB; CONSG(A, 6);
            SB;              CONSG(B, 7);
#undef LOADG
#undef CONSG
#undef LDR
#undef SB
        } else {
            // Generic tail path (not hit at N=262144).
            const int rows = N - rowbase;
            const float4 z4 = make_float4(0.f, 0.f, 0.f, 0.f);
            for (int r = 0; r < rows; ++r) {
                const int   t  = __shfl(t_l,  r, 64);
                const float tl = __shfl(tl_l, r, 64);
                if (t <= 0) continue;
                const float* __restrict__ rp = logits + (size_t)(rowbase + r) * C;
                float4 c0 = z4, c1 = z4;
                if (i0 < t) c0 = *reinterpret_cast<const float4*>(rp + i0);
                if (i1 < t) c1 = *reinterpret_cast<const float4*>(rp + i1);
                acc4(acc, c0, i0, t, tl);
                acc4(acc, c1, i1, t, tl);
            }
        }
    }

    // Wave reduction (64 lanes)
    #pragma unroll
    for (int off = 32; off > 0; off >>= 1)
        acc += __shfl_down(acc, off, 64);

    // Block reduction: 4 waves
    __shared__ float wave_sums[4];
    const int wib = threadIdx.x >> 6;
    if (lane == 0) wave_sums[wib] = acc;
    __syncthreads();
    if (threadIdx.x == 0) {
        const float s = wave_sums[0] + wave_sums[1] + wave_sums[2] + wave_sums[3];
        atomicAdd(out, s);
    }
}

extern "C" void kernel_launch(void* const* d_in, const int* in_sizes, int n_in,
                              void* d_out, int out_size, void* d_ws, size_t ws_size,
                              hipStream_t stream) {
    const float* logits  = (const float*)d_in[0];
    const int*   targets = (const int*)d_in[1];
    float*       out     = (float*)d_out;

    const int N = in_sizes[1];                 // 262144 rows

    // d_out is poisoned and not re-poisoned between replays; we accumulate.
    hipMemsetAsync(out, 0, sizeof(float) * out_size, stream);

    const int block = 256;
    const int rows_per_block = (block / 64) * ROWS_PER_WAVE;    // 128
    const int grid = (N + rows_per_block - 1) / rows_per_block; // 2048
    ordinal_ce_kernel<<<grid, block, 0, stream>>>(logits, targets, out, N);
}